// Round 6
// baseline (251.902 us; speedup 1.0000x reference)
//
#include <hip/hip_runtime.h>
#include <hip/hip_bf16.h>
#include <cstddef>

#define CC   128
#define AD   16
#define VD   64
#define HWN  4096
#define PJ   1024
#define NB   8

typedef short short8 __attribute__((ext_vector_type(8)));
typedef float f32x4  __attribute__((ext_vector_type(4)));
typedef unsigned short u16;

__device__ inline u16 f2bf(float f) {
    __hip_bfloat16 h = __float2bfloat16(f);
    union { __hip_bfloat16 h; u16 u; } c; c.h = h; return c.u;
}
__device__ inline unsigned pk2(float a, float b) {
    __hip_bfloat162 h = __float22bfloat162_rn(make_float2(a, b));
    union { __hip_bfloat162 h; unsigned u; } c; c.h = h; return c.u;
}

// XOR-swizzled physical element index for bf16 LDS tiles (8-elem blocks):
// conflict-free ds_read_b128 MFMA fragment reads.
__device__ inline int ph128(int r, int c) { return r * 128 + ((((c >> 3) ^ (r & 7)) << 3) | (c & 7)); }
__device__ inline int ph64 (int r, int c) { return r * 64  + ((((c >> 3) ^ (r & 7)) << 3) | (c & 7)); }

// async global->LDS, 16B/lane: LDS side is wave-uniform base + lane*16;
// global side is a per-lane (scatter) address.
__device__ inline void stage16(const u16* g, u16* l) {
#if __has_builtin(__builtin_amdgcn_global_load_lds)
    __builtin_amdgcn_global_load_lds(
        (const __attribute__((address_space(1))) unsigned int*)g,
        (__attribute__((address_space(3))) unsigned int*)l, 16, 0, 0);
#else
    *(uint4*)l = *(const uint4*)g;
#endif
}

// ---------------------------------------------------------------------------
// Kernel 1: QKV projection (MFMA, M=64 pos x K=128 ch x N=96) + 2x2 maxpool
// in registers.  Grid (32 strips, 8 batch, 2 half-strips), block 256.
// UNCHANGED from round 5 (this round is a timing-amplification diagnostic).
// ---------------------------------------------------------------------------
__global__ __launch_bounds__(256, 4) void k_proj(
    const float* __restrict__ x,
    const float* __restrict__ Wq, const float* __restrict__ bq,
    const float* __restrict__ Wk, const float* __restrict__ bk,
    const float* __restrict__ Wv, const float* __restrict__ bv,
    u16* __restrict__ Qp, u16* __restrict__ Kp, u16* __restrict__ Vt)
{
    __shared__ __align__(16) u16 xT[64 * 128];   // [local pos][ch] swizzled
    __shared__ __align__(16) u16 WT[96 * 128];   // [n-idx][ch]    swizzled

    const int tile = blockIdx.x, n = blockIdx.y, z = blockIdx.z, t = threadIdx.x;
    const int l = t & 63, w = t >> 6, g = l >> 4, lm = l & 15;
    const int p0 = tile * 128;

    // ---- stage x half-strip: 64 pos x 128 ch, float4 loads, cvt_pk -> b64 ----
    {
        const float* xb = x + (size_t)n * CC * HWN + p0 + z * 32;
#pragma unroll
        for (int it = 0; it < 2; ++it) {
            const int idx = t + 256 * it;             // 0..511
            const int p4 = idx & 15, c4 = idx >> 4;   // pos-quad, ch-quad
            const int gofs = (p4 & 7) * 4 + (p4 >> 3) * 64;
            const float* bp = xb + gofs;
            const f32x4 r0 = *(const f32x4*)(bp + (size_t)(c4 * 4 + 0) * HWN);
            const f32x4 r1 = *(const f32x4*)(bp + (size_t)(c4 * 4 + 1) * HWN);
            const f32x4 r2 = *(const f32x4*)(bp + (size_t)(c4 * 4 + 2) * HWN);
            const f32x4 r3 = *(const f32x4*)(bp + (size_t)(c4 * 4 + 3) * HWN);
#pragma unroll
            for (int pp = 0; pp < 4; ++pp) {
                const int lp = p4 * 4 + pp;
                uint2 v;
                v.x = pk2(r0[pp], r1[pp]);
                v.y = pk2(r2[pp], r3[pp]);
                *(uint2*)&xT[lp * 128 + ((((c4 >> 1) ^ (lp & 7)) << 3) | ((c4 & 1) * 4))] = v;
            }
        }
    }
    // ---- stage W^T: rows 0..15 Wq, 16..31 Wk, 32..95 Wv ----
#pragma unroll
    for (int it = 0; it < 2; ++it) {
        const int idx = t + 256 * it;
        const int d4 = idx & 3, ch = idx >> 2;
        float4 v = *(const float4*)(Wq + ch * AD + d4 * 4);
        WT[ph128(d4 * 4 + 0, ch)] = f2bf(v.x);
        WT[ph128(d4 * 4 + 1, ch)] = f2bf(v.y);
        WT[ph128(d4 * 4 + 2, ch)] = f2bf(v.z);
        WT[ph128(d4 * 4 + 3, ch)] = f2bf(v.w);
        v = *(const float4*)(Wk + ch * AD + d4 * 4);
        WT[ph128(16 + d4 * 4 + 0, ch)] = f2bf(v.x);
        WT[ph128(16 + d4 * 4 + 1, ch)] = f2bf(v.y);
        WT[ph128(16 + d4 * 4 + 2, ch)] = f2bf(v.z);
        WT[ph128(16 + d4 * 4 + 3, ch)] = f2bf(v.w);
    }
#pragma unroll
    for (int it = 0; it < 8; ++it) {
        const int idx = t + 256 * it;
        const int d4 = idx & 15, ch = idx >> 4;
        const float4 v = *(const float4*)(Wv + ch * VD + d4 * 4);
        WT[ph128(32 + d4 * 4 + 0, ch)] = f2bf(v.x);
        WT[ph128(32 + d4 * 4 + 1, ch)] = f2bf(v.y);
        WT[ph128(32 + d4 * 4 + 2, ch)] = f2bf(v.z);
        WT[ph128(32 + d4 * 4 + 3, ch)] = f2bf(v.w);
    }
    __syncthreads();

    // ---- MFMA: wave w -> pool-pair pw=w&1 (m-tiles pw, pw+2), n-group ng=w>>1
    const int pw = w & 1, ng = w >> 1;
    f32x4 acc[2][3];
#pragma unroll
    for (int i = 0; i < 2; ++i)
#pragma unroll
        for (int j = 0; j < 3; ++j) acc[i][j] = (f32x4){0.f, 0.f, 0.f, 0.f};
#pragma unroll
    for (int ks = 0; ks < 4; ++ks) {
        const short8 a0 = *(const short8*)&xT[ph128(pw * 16 + lm,      ks * 32 + g * 8)];
        const short8 a1 = *(const short8*)&xT[ph128(32 + pw * 16 + lm, ks * 32 + g * 8)];
#pragma unroll
        for (int j = 0; j < 3; ++j) {
            const short8 b = *(const short8*)&WT[ph128((ng * 3 + j) * 16 + lm, ks * 32 + g * 8)];
            acc[0][j] = __builtin_amdgcn_mfma_f32_16x16x32_bf16(a0, b, acc[0][j], 0, 0, 0);
            acc[1][j] = __builtin_amdgcn_mfma_f32_16x16x32_bf16(a1, b, acc[1][j], 0, 0, 0);
        }
    }

    // ---- register epilogue: C row = g*4+r, col = lm ----
    const int pbase = p0 + z * 32 + pw * 16 + g * 4;         // global pos, acc[0] row r=0
    const int jp = tile * 32 + z * 16 + pw * 8 + g * 2;      // pooled j base (even)

    if (ng == 0) {
        // Q (+bq)
        const float bqv = bq[lm];
#pragma unroll
        for (int mi = 0; mi < 2; ++mi)
#pragma unroll
            for (int r = 0; r < 4; ++r)
                Qp[((size_t)n * HWN + pbase + mi * 64 + r) * AD + lm] = f2bf(acc[mi][0][r] + bqv);
        // K pooled (+bk)
        const float bkv = bk[lm];
#pragma unroll
        for (int a = 0; a < 2; ++a) {
            const float m = fmaxf(fmaxf(acc[0][1][2 * a], acc[0][1][2 * a + 1]),
                                  fmaxf(acc[1][1][2 * a], acc[1][1][2 * a + 1])) + bkv;
            Kp[((size_t)n * PJ + jp + a) * AD + lm] = f2bf(m);
        }
        // V pooled dv 0..15 (+bv)
        {
            const float bvv = bv[lm];
            const float m0 = fmaxf(fmaxf(acc[0][2][0], acc[0][2][1]),
                                   fmaxf(acc[1][2][0], acc[1][2][1])) + bvv;
            const float m1 = fmaxf(fmaxf(acc[0][2][2], acc[0][2][3]),
                                   fmaxf(acc[1][2][2], acc[1][2][3])) + bvv;
            *(unsigned*)&Vt[((size_t)n * VD + lm) * PJ + jp] = pk2(m0, m1);
        }
    } else {
        // V pooled dv 16..63 (+bv)
#pragma unroll
        for (int j = 0; j < 3; ++j) {
            const int dv = (j + 1) * 16 + lm;
            const float bvv = bv[dv];
            const float m0 = fmaxf(fmaxf(acc[0][j][0], acc[0][j][1]),
                                   fmaxf(acc[1][j][0], acc[1][j][1])) + bvv;
            const float m1 = fmaxf(fmaxf(acc[0][j][2], acc[0][j][3]),
                                   fmaxf(acc[1][j][2], acc[1][j][3])) + bvv;
            *(unsigned*)&Vt[((size_t)n * VD + dv) * PJ + jp] = pk2(m0, m1);
        }
    }
}

// ---------------------------------------------------------------------------
// Kernel 2: flash attention + out-proj + residual, all MFMA.
// UNCHANGED from round 5.
// ---------------------------------------------------------------------------
__global__ __launch_bounds__(256, 4) void k_attn(
    const float* __restrict__ x,
    const u16* __restrict__ Qp, const u16* __restrict__ Kp, const u16* __restrict__ Vt,
    const float* __restrict__ Wo, const float* __restrict__ bo,
    const float* __restrict__ gma,
    float* __restrict__ out)
{
    __shared__ __align__(16) u16 KVl[10240];     // K 2048 elems | V 8192 elems
    __shared__ __align__(16) u16 PB[4 * 2048];   // per-wave P; reused as O^T

    const int n = blockIdx.y, t = threadIdx.x;
    const int q0b = blockIdx.x * 64;
    const int l = t & 63, w = t >> 6, g = l >> 4, lm = l & 15;

    // Q A-frag (g>=2 lanes are the K=16..31 zero pad)
    short8 qf = {0, 0, 0, 0, 0, 0, 0, 0};
    if (g < 2)
        qf = *(const short8*)(Qp + ((size_t)n * HWN + q0b + w * 16 + lm) * AD + g * 8);

    // per-lane global source addresses for staging (swizzle on global side)
    const u16* Kg = Kp + (size_t)n * PJ * AD
                  + (size_t)(t >> 1) * AD + ((t & 1) ^ ((t >> 1) & 1)) * 8;
    const int vdv0 = (w * 4) * 4 + (l >> 4);                 // dv for i=0
    const u16* Vg0 = Vt + ((size_t)n * VD) * PJ;

    u16* Vl = KVl + 2048;
    u16* Pl = PB + w * 2048;

    f32x4 O[4];
#pragma unroll
    for (int i = 0; i < 4; ++i) O[i] = (f32x4){0.f, 0.f, 0.f, 0.f};
    float mr[4] = {-1e30f, -1e30f, -1e30f, -1e30f};
    float lr[4] = {0.f, 0.f, 0.f, 0.f};

    for (int ch = 0; ch < 8; ++ch) {
        const int j0 = ch * 128;
        // ---- stage K chunk: lane t -> LDS elems t*8..t*8+7 ----
        stage16(Kg + (size_t)j0 * AD, &KVl[t * 8]);
        // ---- stage V chunk: lane (w,i,l) -> dv = (w*4+i)*4 + l>>4, block l&15
#pragma unroll
        for (int i = 0; i < 4; ++i) {
            const int dv = vdv0 + i * 4;
            stage16(Vg0 + (size_t)dv * PJ + j0 + (((l & 15) ^ (dv & 7)) * 8),
                    &Vl[(w * 4 + i) * 512 + l * 8]);
        }
        __syncthreads();

        // ---- scores: 8 j-tiles of 16, K=32 (d zero-padded) ----
        f32x4 S[8];
#pragma unroll
        for (int jt = 0; jt < 8; ++jt) {
            short8 kb = {0, 0, 0, 0, 0, 0, 0, 0};
            if (g < 2) {
                const int j = jt * 16 + lm;
                kb = *(const short8*)&KVl[(j * 2 + (g ^ (j & 1))) * 8];
            }
            const f32x4 z = (f32x4){0.f, 0.f, 0.f, 0.f};
            S[jt] = __builtin_amdgcn_mfma_f32_16x16x32_bf16(qf, kb, z, 0, 0, 0);
        }

        // ---- online softmax (C layout: row=g*4+r, col=jt*16+lm) ----
#pragma unroll
        for (int r = 0; r < 4; ++r) {
            float cm = S[0][r];
#pragma unroll
            for (int jt = 1; jt < 8; ++jt) cm = fmaxf(cm, S[jt][r]);
            cm = fmaxf(cm, __shfl_xor(cm, 1));
            cm = fmaxf(cm, __shfl_xor(cm, 2));
            cm = fmaxf(cm, __shfl_xor(cm, 4));
            cm = fmaxf(cm, __shfl_xor(cm, 8));
            const float nm = fmaxf(mr[r], cm);
            const float al = __expf(mr[r] - nm);
            mr[r] = nm;
            const int row = g * 4 + r;
            float sum = 0.f;
#pragma unroll
            for (int jt = 0; jt < 8; ++jt) {
                const float p = __expf(S[jt][r] - nm);
                sum += p;
                Pl[ph128(row, jt * 16 + lm)] = f2bf(p);
            }
            sum += __shfl_xor(sum, 1);
            sum += __shfl_xor(sum, 2);
            sum += __shfl_xor(sum, 4);
            sum += __shfl_xor(sum, 8);
            lr[r] = lr[r] * al + sum;
            O[0][r] *= al; O[1][r] *= al; O[2][r] *= al; O[3][r] *= al;
        }

        // ---- P @ V ----
#pragma unroll
        for (int ks = 0; ks < 4; ++ks) {
            const short8 pf = *(const short8*)&Pl[ph128(lm, ks * 32 + g * 8)];
#pragma unroll
            for (int dt = 0; dt < 4; ++dt) {
                const short8 vf = *(const short8*)&Vl[ph128(dt * 16 + lm, ks * 32 + g * 8)];
                O[dt] = __builtin_amdgcn_mfma_f32_16x16x32_bf16(pf, vf, O[dt], 0, 0, 0);
            }
        }
        __syncthreads();   // all waves done with KVl before next stage
    }

    // ---- normalize, O^T -> per-wave LDS (B-frag for out-proj) ----
    u16* Ol = Pl;
#pragma unroll
    for (int r = 0; r < 4; ++r) {
        const float inv = 1.f / lr[r];
        const int row = g * 4 + r;
#pragma unroll
        for (int dt = 0; dt < 4; ++dt)
            Ol[ph64(row, dt * 16 + lm)] = f2bf(O[dt][r] * inv);
    }
    // ---- stage WoT[c][dv] into KVl (dead after final chunk barrier) ----
#pragma unroll
    for (int it = 0; it < 8; ++it) {
        const int idx = t + 256 * it;
        const int c4 = idx & 31, dv = idx >> 5;
        const float4 v = *(const float4*)(Wo + dv * CC + c4 * 4);
        KVl[ph64(c4 * 4 + 0, dv)] = f2bf(v.x);
        KVl[ph64(c4 * 4 + 1, dv)] = f2bf(v.y);
        KVl[ph64(c4 * 4 + 2, dv)] = f2bf(v.z);
        KVl[ph64(c4 * 4 + 3, dv)] = f2bf(v.w);
    }
    __syncthreads();

    // ---- out-proj: D[c][q] = WoT(c,dv) @ O^T(dv,q); residual + store ----
    const float gm = gma[0];
#pragma unroll
    for (int mt = 0; mt < 8; ++mt) {
        float xr[4];
        const size_t obase = ((size_t)n * CC + mt * 16 + g * 4) * HWN + q0b + w * 16 + lm;
#pragma unroll
        for (int r = 0; r < 4; ++r) xr[r] = x[obase + (size_t)r * HWN];
        f32x4 D = (f32x4){0.f, 0.f, 0.f, 0.f};
#pragma unroll
        for (int ks = 0; ks < 2; ++ks) {
            const short8 af = *(const short8*)&KVl[ph64(mt * 16 + lm, ks * 32 + g * 8)];
            const short8 bf = *(const short8*)&Ol[ph64(lm, ks * 32 + g * 8)];
            D = __builtin_amdgcn_mfma_f32_16x16x32_bf16(af, bf, D, 0, 0, 0);
        }
#pragma unroll
        for (int r = 0; r < 4; ++r) {
            const int c = mt * 16 + g * 4 + r;
            out[obase + (size_t)r * HWN] = xr[r] + gm * (D[r] + bo[c]);
        }
    }
}

extern "C" void kernel_launch(void* const* d_in, const int* in_sizes, int n_in,
                              void* d_out, int out_size, void* d_ws, size_t ws_size,
                              hipStream_t stream) {
    const float* x     = (const float*)d_in[0];
    const float* Wq    = (const float*)d_in[1];
    const float* bq    = (const float*)d_in[2];
    const float* Wk    = (const float*)d_in[3];
    const float* bk    = (const float*)d_in[4];
    const float* Wv    = (const float*)d_in[5];
    const float* bv    = (const float*)d_in[6];
    const float* Wo    = (const float*)d_in[7];
    const float* bo    = (const float*)d_in[8];
    const float* gamma = (const float*)d_in[9];
    float* out = (float*)d_out;

    u16* Qp = (u16*)d_ws;                        // 8*4096*16 bf16 = 1 MB
    u16* Kp = Qp + (size_t)NB * HWN * AD;        // 8*1024*16 bf16 = 256 KB
    u16* Vt = Kp + (size_t)NB * PJ * AD;         // 8*64*1024 bf16 = 1 MB

    // DIAGNOSTIC ROUND: launch the identical (idempotent) pair 4x to measure
    // true kernel time through the fixed harness overhead:
    //   dur = F + 4*K;  round-5 gave F + K = 124.7  =>  K = (dur - 124.7)/3.
    for (int rep = 0; rep < 4; ++rep) {
        k_proj<<<dim3(32, NB, 2), 256, 0, stream>>>(x, Wq, bq, Wk, bk, Wv, bv, Qp, Kp, Vt);
        k_attn<<<dim3(64, NB), 256, 0, stream>>>(x, Qp, Kp, Vt, Wo, bo, gamma, out);
    }
}

// Round 7
// 188.022 us; speedup vs baseline: 1.3397x; 1.3397x over previous
//
#include <hip/hip_runtime.h>
#include <hip/hip_bf16.h>
#include <hip/hip_cooperative_groups.h>
#include <cstddef>

#define CC   128
#define AD   16
#define VD   64
#define HWN  4096
#define PJ   1024
#define NB   8

namespace cg = cooperative_groups;

typedef short short8 __attribute__((ext_vector_type(8)));
typedef float f32x4  __attribute__((ext_vector_type(4)));
typedef unsigned short u16;

__device__ inline u16 f2bf(float f) {
    __hip_bfloat16 h = __float2bfloat16(f);
    union { __hip_bfloat16 h; u16 u; } c; c.h = h; return c.u;
}
__device__ inline unsigned pk2(float a, float b) {
    __hip_bfloat162 h = __float22bfloat162_rn(make_float2(a, b));
    union { __hip_bfloat162 h; unsigned u; } c; c.h = h; return c.u;
}

// XOR-swizzled physical element index for bf16 LDS tiles (8-elem blocks):
// conflict-free ds_read_b128 MFMA fragment reads.
__device__ inline int ph128(int r, int c) { return r * 128 + ((((c >> 3) ^ (r & 7)) << 3) | (c & 7)); }
__device__ inline int ph64 (int r, int c) { return r * 64  + ((((c >> 3) ^ (r & 7)) << 3) | (c & 7)); }

// async global->LDS, 16B/lane: LDS side is wave-uniform base + lane*16;
// global side is a per-lane (scatter) address.
__device__ inline void stage16(const u16* g, u16* l) {
#if __has_builtin(__builtin_amdgcn_global_load_lds)
    __builtin_amdgcn_global_load_lds(
        (const __attribute__((address_space(1))) unsigned int*)g,
        (__attribute__((address_space(3))) unsigned int*)l, 16, 0, 0);
#else
    *(uint4*)l = *(const uint4*)g;
#endif
}

// ---------------------------------------------------------------------------
// Fused cooperative kernel.  Grid 512 blocks x 256 thr, 40 KB LDS union,
// 2 blocks/CU co-resident (coop launch requirement satisfied: 512 <= 1024).
//   Phase 1 (== round-5 k_proj): QKV projection MFMA + register 2x2 maxpool.
//     block b -> tile = b&31, n = (b>>5)&7, z = b>>8.
//   grid.sync()  (device-scope fence: ws bf16 tensors visible cross-XCD)
//   Phase 2 (== round-5 k_attn): flash attention + out-proj + residual.
//     block b -> q-tile = b&63, n = b>>6.
// Rationale this round: K_total(two kernels) = 42 us measured via 4x-rep
// amplification, but static cycle models put execution at ~12 us -> the
// difference is per-dispatch ramp/drain/gap.  Fusing 2 dispatches -> 1.
// ---------------------------------------------------------------------------
__global__ __launch_bounds__(256, 4) void k_fused(
    const float* __restrict__ x,
    const float* __restrict__ Wq, const float* __restrict__ bq,
    const float* __restrict__ Wk, const float* __restrict__ bk,
    const float* __restrict__ Wv, const float* __restrict__ bv,
    const float* __restrict__ Wo, const float* __restrict__ bo,
    const float* __restrict__ gma,
    u16* __restrict__ Qp, u16* __restrict__ Kp, u16* __restrict__ Vt,
    float* __restrict__ out)
{
    __shared__ __align__(16) u16 smem[20480];    // 40 KB union

    const int b = blockIdx.x, t = threadIdx.x;
    const int l = t & 63, w = t >> 6, g = l >> 4, lm = l & 15;

    // =====================================================================
    // Phase 1: projection + pool
    // =====================================================================
    {
        u16* xT = smem;           // [64 pos][128 ch] swizzled (8192)
        u16* WT = smem + 8192;    // [96 n-idx][128 ch] swizzled (12288)

        const int tile = b & 31, n = (b >> 5) & 7, z = b >> 8;
        const int p0 = tile * 128;

        // ---- stage x half-strip: 64 pos x 128 ch ----
        {
            const float* xb = x + (size_t)n * CC * HWN + p0 + z * 32;
#pragma unroll
            for (int it = 0; it < 2; ++it) {
                const int idx = t + 256 * it;             // 0..511
                const int p4 = idx & 15, c4 = idx >> 4;
                const int gofs = (p4 & 7) * 4 + (p4 >> 3) * 64;
                const float* bp = xb + gofs;
                const f32x4 r0 = *(const f32x4*)(bp + (size_t)(c4 * 4 + 0) * HWN);
                const f32x4 r1 = *(const f32x4*)(bp + (size_t)(c4 * 4 + 1) * HWN);
                const f32x4 r2 = *(const f32x4*)(bp + (size_t)(c4 * 4 + 2) * HWN);
                const f32x4 r3 = *(const f32x4*)(bp + (size_t)(c4 * 4 + 3) * HWN);
#pragma unroll
                for (int pp = 0; pp < 4; ++pp) {
                    const int lp = p4 * 4 + pp;
                    uint2 v;
                    v.x = pk2(r0[pp], r1[pp]);
                    v.y = pk2(r2[pp], r3[pp]);
                    *(uint2*)&xT[lp * 128 + ((((c4 >> 1) ^ (lp & 7)) << 3) | ((c4 & 1) * 4))] = v;
                }
            }
        }
        // ---- stage W^T: rows 0..15 Wq, 16..31 Wk, 32..95 Wv ----
#pragma unroll
        for (int it = 0; it < 2; ++it) {
            const int idx = t + 256 * it;
            const int d4 = idx & 3, ch = idx >> 2;
            float4 v = *(const float4*)(Wq + ch * AD + d4 * 4);
            WT[ph128(d4 * 4 + 0, ch)] = f2bf(v.x);
            WT[ph128(d4 * 4 + 1, ch)] = f2bf(v.y);
            WT[ph128(d4 * 4 + 2, ch)] = f2bf(v.z);
            WT[ph128(d4 * 4 + 3, ch)] = f2bf(v.w);
            v = *(const float4*)(Wk + ch * AD + d4 * 4);
            WT[ph128(16 + d4 * 4 + 0, ch)] = f2bf(v.x);
            WT[ph128(16 + d4 * 4 + 1, ch)] = f2bf(v.y);
            WT[ph128(16 + d4 * 4 + 2, ch)] = f2bf(v.z);
            WT[ph128(16 + d4 * 4 + 3, ch)] = f2bf(v.w);
        }
#pragma unroll
        for (int it = 0; it < 8; ++it) {
            const int idx = t + 256 * it;
            const int d4 = idx & 15, ch = idx >> 4;
            const float4 v = *(const float4*)(Wv + ch * VD + d4 * 4);
            WT[ph128(32 + d4 * 4 + 0, ch)] = f2bf(v.x);
            WT[ph128(32 + d4 * 4 + 1, ch)] = f2bf(v.y);
            WT[ph128(32 + d4 * 4 + 2, ch)] = f2bf(v.z);
            WT[ph128(32 + d4 * 4 + 3, ch)] = f2bf(v.w);
        }
        __syncthreads();

        // ---- MFMA: wave w -> pool-pair pw=w&1 (m-tiles pw,pw+2), ng=w>>1 ----
        const int pw = w & 1, ng = w >> 1;
        f32x4 acc[2][3];
#pragma unroll
        for (int i = 0; i < 2; ++i)
#pragma unroll
            for (int j = 0; j < 3; ++j) acc[i][j] = (f32x4){0.f, 0.f, 0.f, 0.f};
#pragma unroll
        for (int ks = 0; ks < 4; ++ks) {
            const short8 a0 = *(const short8*)&xT[ph128(pw * 16 + lm,      ks * 32 + g * 8)];
            const short8 a1 = *(const short8*)&xT[ph128(32 + pw * 16 + lm, ks * 32 + g * 8)];
#pragma unroll
            for (int j = 0; j < 3; ++j) {
                const short8 bb = *(const short8*)&WT[ph128((ng * 3 + j) * 16 + lm, ks * 32 + g * 8)];
                acc[0][j] = __builtin_amdgcn_mfma_f32_16x16x32_bf16(a0, bb, acc[0][j], 0, 0, 0);
                acc[1][j] = __builtin_amdgcn_mfma_f32_16x16x32_bf16(a1, bb, acc[1][j], 0, 0, 0);
            }
        }

        // ---- register epilogue: C row = g*4+r, col = lm ----
        const int pbase = p0 + z * 32 + pw * 16 + g * 4;
        const int jp = tile * 32 + z * 16 + pw * 8 + g * 2;

        if (ng == 0) {
            const float bqv = bq[lm];
#pragma unroll
            for (int mi = 0; mi < 2; ++mi)
#pragma unroll
                for (int r = 0; r < 4; ++r)
                    Qp[((size_t)n * HWN + pbase + mi * 64 + r) * AD + lm] = f2bf(acc[mi][0][r] + bqv);
            const float bkv = bk[lm];
#pragma unroll
            for (int a = 0; a < 2; ++a) {
                const float m = fmaxf(fmaxf(acc[0][1][2 * a], acc[0][1][2 * a + 1]),
                                      fmaxf(acc[1][1][2 * a], acc[1][1][2 * a + 1])) + bkv;
                Kp[((size_t)n * PJ + jp + a) * AD + lm] = f2bf(m);
            }
            {
                const float bvv = bv[lm];
                const float m0 = fmaxf(fmaxf(acc[0][2][0], acc[0][2][1]),
                                       fmaxf(acc[1][2][0], acc[1][2][1])) + bvv;
                const float m1 = fmaxf(fmaxf(acc[0][2][2], acc[0][2][3]),
                                       fmaxf(acc[1][2][2], acc[1][2][3])) + bvv;
                *(unsigned*)&Vt[((size_t)n * VD + lm) * PJ + jp] = pk2(m0, m1);
            }
        } else {
#pragma unroll
            for (int j = 0; j < 3; ++j) {
                const int dv = (j + 1) * 16 + lm;
                const float bvv = bv[dv];
                const float m0 = fmaxf(fmaxf(acc[0][j][0], acc[0][j][1]),
                                       fmaxf(acc[1][j][0], acc[1][j][1])) + bvv;
                const float m1 = fmaxf(fmaxf(acc[0][j][2], acc[0][j][3]),
                                       fmaxf(acc[1][j][2], acc[1][j][3])) + bvv;
                *(unsigned*)&Vt[((size_t)n * VD + dv) * PJ + jp] = pk2(m0, m1);
            }
        }
    }

    // =====================================================================
    // grid-wide sync: all ws writes visible device-wide
    // =====================================================================
    cg::this_grid().sync();

    // =====================================================================
    // Phase 2: flash attention + out-proj + residual
    // =====================================================================
    {
        u16* KVl = smem;            // K 2048 | V 8192
        u16* Vl  = smem + 2048;
        u16* PB  = smem + 10240;    // 4 waves x 2048
        u16* Pl  = PB + w * 2048;

        const int n = b >> 6;
        const int q0b = (b & 63) * 64;

        // Q A-frag (g>=2 lanes are the K=16..31 zero pad)
        short8 qf = {0, 0, 0, 0, 0, 0, 0, 0};
        if (g < 2)
            qf = *(const short8*)(Qp + ((size_t)n * HWN + q0b + w * 16 + lm) * AD + g * 8);

        // per-lane global source addresses (swizzle on global side)
        const u16* Kg = Kp + (size_t)n * PJ * AD
                      + (size_t)(t >> 1) * AD + ((t & 1) ^ ((t >> 1) & 1)) * 8;
        const int vdv0 = (w * 4) * 4 + (l >> 4);
        const u16* Vg0 = Vt + ((size_t)n * VD) * PJ;

        f32x4 O[4];
#pragma unroll
        for (int i = 0; i < 4; ++i) O[i] = (f32x4){0.f, 0.f, 0.f, 0.f};
        float mr[4] = {-1e30f, -1e30f, -1e30f, -1e30f};
        float lr[4] = {0.f, 0.f, 0.f, 0.f};

        for (int ch = 0; ch < 8; ++ch) {
            const int j0 = ch * 128;
            stage16(Kg + (size_t)j0 * AD, &KVl[t * 8]);
#pragma unroll
            for (int i = 0; i < 4; ++i) {
                const int dv = vdv0 + i * 4;
                stage16(Vg0 + (size_t)dv * PJ + j0 + (((l & 15) ^ (dv & 7)) * 8),
                        &Vl[(w * 4 + i) * 512 + l * 8]);
            }
            __syncthreads();

            // ---- scores ----
            f32x4 S[8];
#pragma unroll
            for (int jt = 0; jt < 8; ++jt) {
                short8 kb = {0, 0, 0, 0, 0, 0, 0, 0};
                if (g < 2) {
                    const int j = jt * 16 + lm;
                    kb = *(const short8*)&KVl[(j * 2 + (g ^ (j & 1))) * 8];
                }
                const f32x4 z4 = (f32x4){0.f, 0.f, 0.f, 0.f};
                S[jt] = __builtin_amdgcn_mfma_f32_16x16x32_bf16(qf, kb, S[jt] = z4, 0, 0, 0);
            }

            // ---- online softmax (C layout: row=g*4+r, col=jt*16+lm) ----
#pragma unroll
            for (int r = 0; r < 4; ++r) {
                float cm = S[0][r];
#pragma unroll
                for (int jt = 1; jt < 8; ++jt) cm = fmaxf(cm, S[jt][r]);
                cm = fmaxf(cm, __shfl_xor(cm, 1));
                cm = fmaxf(cm, __shfl_xor(cm, 2));
                cm = fmaxf(cm, __shfl_xor(cm, 4));
                cm = fmaxf(cm, __shfl_xor(cm, 8));
                const float nm = fmaxf(mr[r], cm);
                const float al = __expf(mr[r] - nm);
                mr[r] = nm;
                const int row = g * 4 + r;
                float sum = 0.f;
#pragma unroll
                for (int jt = 0; jt < 8; ++jt) {
                    const float p = __expf(S[jt][r] - nm);
                    sum += p;
                    Pl[ph128(row, jt * 16 + lm)] = f2bf(p);
                }
                sum += __shfl_xor(sum, 1);
                sum += __shfl_xor(sum, 2);
                sum += __shfl_xor(sum, 4);
                sum += __shfl_xor(sum, 8);
                lr[r] = lr[r] * al + sum;
                O[0][r] *= al; O[1][r] *= al; O[2][r] *= al; O[3][r] *= al;
            }

            // ---- P @ V ----
#pragma unroll
            for (int ks = 0; ks < 4; ++ks) {
                const short8 pf = *(const short8*)&Pl[ph128(lm, ks * 32 + g * 8)];
#pragma unroll
                for (int dt = 0; dt < 4; ++dt) {
                    const short8 vf = *(const short8*)&Vl[ph128(dt * 16 + lm, ks * 32 + g * 8)];
                    O[dt] = __builtin_amdgcn_mfma_f32_16x16x32_bf16(pf, vf, O[dt], 0, 0, 0);
                }
            }
            __syncthreads();
        }

        // ---- normalize, O^T -> per-wave LDS ----
        u16* Ol = Pl;
#pragma unroll
        for (int r = 0; r < 4; ++r) {
            const float inv = 1.f / lr[r];
            const int row = g * 4 + r;
#pragma unroll
            for (int dt = 0; dt < 4; ++dt)
                Ol[ph64(row, dt * 16 + lm)] = f2bf(O[dt][r] * inv);
        }
        // ---- stage WoT[c][dv] into KVl ----
#pragma unroll
        for (int it = 0; it < 8; ++it) {
            const int idx = t + 256 * it;
            const int c4 = idx & 31, dv = idx >> 5;
            const float4 v = *(const float4*)(Wo + dv * CC + c4 * 4);
            KVl[ph64(c4 * 4 + 0, dv)] = f2bf(v.x);
            KVl[ph64(c4 * 4 + 1, dv)] = f2bf(v.y);
            KVl[ph64(c4 * 4 + 2, dv)] = f2bf(v.z);
            KVl[ph64(c4 * 4 + 3, dv)] = f2bf(v.w);
        }
        __syncthreads();

        // ---- out-proj + residual ----
        const float gm = gma[0];
#pragma unroll
        for (int mt = 0; mt < 8; ++mt) {
            float xr[4];
            const size_t obase = ((size_t)n * CC + mt * 16 + g * 4) * HWN + q0b + w * 16 + lm;
#pragma unroll
            for (int r = 0; r < 4; ++r) xr[r] = x[obase + (size_t)r * HWN];
            f32x4 D = (f32x4){0.f, 0.f, 0.f, 0.f};
#pragma unroll
            for (int ks = 0; ks < 2; ++ks) {
                const short8 af = *(const short8*)&KVl[ph64(mt * 16 + lm, ks * 32 + g * 8)];
                const short8 bf = *(const short8*)&Ol[ph64(lm, ks * 32 + g * 8)];
                D = __builtin_amdgcn_mfma_f32_16x16x32_bf16(af, bf, D, 0, 0, 0);
            }
#pragma unroll
            for (int r = 0; r < 4; ++r) {
                const int c = mt * 16 + g * 4 + r;
                out[obase + (size_t)r * HWN] = xr[r] + gm * (D[r] + bo[c]);
            }
        }
    }
}

extern "C" void kernel_launch(void* const* d_in, const int* in_sizes, int n_in,
                              void* d_out, int out_size, void* d_ws, size_t ws_size,
                              hipStream_t stream) {
    const float* x     = (const float*)d_in[0];
    const float* Wq    = (const float*)d_in[1];
    const float* bq    = (const float*)d_in[2];
    const float* Wk    = (const float*)d_in[3];
    const float* bk    = (const float*)d_in[4];
    const float* Wv    = (const float*)d_in[5];
    const float* bv    = (const float*)d_in[6];
    const float* Wo    = (const float*)d_in[7];
    const float* bo    = (const float*)d_in[8];
    const float* gamma = (const float*)d_in[9];
    float* out = (float*)d_out;

    u16* Qp = (u16*)d_ws;                        // 8*4096*16 bf16 = 1 MB
    u16* Kp = Qp + (size_t)NB * HWN * AD;        // 8*1024*16 bf16 = 256 KB
    u16* Vt = Kp + (size_t)NB * PJ * AD;         // 8*64*1024 bf16 = 1 MB

    void* args[] = {
        (void*)&x,  (void*)&Wq, (void*)&bq, (void*)&Wk, (void*)&bk,
        (void*)&Wv, (void*)&bv, (void*)&Wo, (void*)&bo, (void*)&gamma,
        (void*)&Qp, (void*)&Kp, (void*)&Vt, (void*)&out
    };
    hipLaunchCooperativeKernel((const void*)k_fused, dim3(512), dim3(256),
                               args, 0, stream);
}

// Round 8
// 114.411 us; speedup vs baseline: 2.2017x; 1.6434x over previous
//
#include <hip/hip_runtime.h>
#include <hip/hip_bf16.h>
#include <cstddef>

#define CC   128
#define AD   16
#define VD   64
#define HWN  4096
#define PJ   1024
#define NB   8

typedef short short8 __attribute__((ext_vector_type(8)));
typedef float f32x4  __attribute__((ext_vector_type(4)));
typedef unsigned short u16;

__device__ inline u16 f2bf(float f) {
    __hip_bfloat16 h = __float2bfloat16(f);
    union { __hip_bfloat16 h; u16 u; } c; c.h = h; return c.u;
}
__device__ inline unsigned pk2(float a, float b) {
    __hip_bfloat162 h = __float22bfloat162_rn(make_float2(a, b));
    union { __hip_bfloat162 h; unsigned u; } c; c.h = h; return c.u;
}

// XOR-swizzled physical element index for bf16 LDS tiles (8-elem blocks):
// conflict-free ds_read_b128 MFMA fragment reads.
__device__ inline int ph128(int r, int c) { return r * 128 + ((((c >> 3) ^ (r & 7)) << 3) | (c & 7)); }
__device__ inline int ph64 (int r, int c) { return r * 64  + ((((c >> 3) ^ (r & 7)) << 3) | (c & 7)); }

// async global->LDS, 16B/lane: LDS side is wave-uniform base + lane*16;
// global side is a per-lane (scatter) address.
__device__ inline void stage16(const u16* g, u16* l) {
#if __has_builtin(__builtin_amdgcn_global_load_lds)
    __builtin_amdgcn_global_load_lds(
        (const __attribute__((address_space(1))) unsigned int*)g,
        (__attribute__((address_space(3))) unsigned int*)l, 16, 0, 0);
#else
    *(uint4*)l = *(const uint4*)g;
#endif
}

// ---------------------------------------------------------------------------
// Kernel 1: QKV projection (MFMA, M=64 pos x K=128 ch x N=96) + 2x2 maxpool
// in registers.  UNCHANGED from round 5 (proven).
// Outputs bf16: Qp[n][4096][16], Kp[n][1024][16], Vt[n][64][1024].
// ---------------------------------------------------------------------------
__global__ __launch_bounds__(256, 4) void k_proj(
    const float* __restrict__ x,
    const float* __restrict__ Wq, const float* __restrict__ bq,
    const float* __restrict__ Wk, const float* __restrict__ bk,
    const float* __restrict__ Wv, const float* __restrict__ bv,
    u16* __restrict__ Qp, u16* __restrict__ Kp, u16* __restrict__ Vt)
{
    __shared__ __align__(16) u16 xT[64 * 128];   // [local pos][ch] swizzled
    __shared__ __align__(16) u16 WT[96 * 128];   // [n-idx][ch]    swizzled

    const int tile = blockIdx.x, n = blockIdx.y, z = blockIdx.z, t = threadIdx.x;
    const int l = t & 63, w = t >> 6, g = l >> 4, lm = l & 15;
    const int p0 = tile * 128;

    // ---- stage x half-strip: 64 pos x 128 ch, float4 loads, cvt_pk -> b64 ----
    {
        const float* xb = x + (size_t)n * CC * HWN + p0 + z * 32;
#pragma unroll
        for (int it = 0; it < 2; ++it) {
            const int idx = t + 256 * it;             // 0..511
            const int p4 = idx & 15, c4 = idx >> 4;   // pos-quad, ch-quad
            const int gofs = (p4 & 7) * 4 + (p4 >> 3) * 64;
            const float* bp = xb + gofs;
            const f32x4 r0 = *(const f32x4*)(bp + (size_t)(c4 * 4 + 0) * HWN);
            const f32x4 r1 = *(const f32x4*)(bp + (size_t)(c4 * 4 + 1) * HWN);
            const f32x4 r2 = *(const f32x4*)(bp + (size_t)(c4 * 4 + 2) * HWN);
            const f32x4 r3 = *(const f32x4*)(bp + (size_t)(c4 * 4 + 3) * HWN);
#pragma unroll
            for (int pp = 0; pp < 4; ++pp) {
                const int lp = p4 * 4 + pp;
                uint2 v;
                v.x = pk2(r0[pp], r1[pp]);
                v.y = pk2(r2[pp], r3[pp]);
                *(uint2*)&xT[lp * 128 + ((((c4 >> 1) ^ (lp & 7)) << 3) | ((c4 & 1) * 4))] = v;
            }
        }
    }
    // ---- stage W^T: rows 0..15 Wq, 16..31 Wk, 32..95 Wv ----
#pragma unroll
    for (int it = 0; it < 2; ++it) {
        const int idx = t + 256 * it;
        const int d4 = idx & 3, ch = idx >> 2;
        float4 v = *(const float4*)(Wq + ch * AD + d4 * 4);
        WT[ph128(d4 * 4 + 0, ch)] = f2bf(v.x);
        WT[ph128(d4 * 4 + 1, ch)] = f2bf(v.y);
        WT[ph128(d4 * 4 + 2, ch)] = f2bf(v.z);
        WT[ph128(d4 * 4 + 3, ch)] = f2bf(v.w);
        v = *(const float4*)(Wk + ch * AD + d4 * 4);
        WT[ph128(16 + d4 * 4 + 0, ch)] = f2bf(v.x);
        WT[ph128(16 + d4 * 4 + 1, ch)] = f2bf(v.y);
        WT[ph128(16 + d4 * 4 + 2, ch)] = f2bf(v.z);
        WT[ph128(16 + d4 * 4 + 3, ch)] = f2bf(v.w);
    }
#pragma unroll
    for (int it = 0; it < 8; ++it) {
        const int idx = t + 256 * it;
        const int d4 = idx & 15, ch = idx >> 4;
        const float4 v = *(const float4*)(Wv + ch * VD + d4 * 4);
        WT[ph128(32 + d4 * 4 + 0, ch)] = f2bf(v.x);
        WT[ph128(32 + d4 * 4 + 1, ch)] = f2bf(v.y);
        WT[ph128(32 + d4 * 4 + 2, ch)] = f2bf(v.z);
        WT[ph128(32 + d4 * 4 + 3, ch)] = f2bf(v.w);
    }
    __syncthreads();

    // ---- MFMA: wave w -> pool-pair pw=w&1 (m-tiles pw,pw+2), ng=w>>1 ----
    const int pw = w & 1, ng = w >> 1;
    f32x4 acc[2][3];
#pragma unroll
    for (int i = 0; i < 2; ++i)
#pragma unroll
        for (int j = 0; j < 3; ++j) acc[i][j] = (f32x4){0.f, 0.f, 0.f, 0.f};
#pragma unroll
    for (int ks = 0; ks < 4; ++ks) {
        const short8 a0 = *(const short8*)&xT[ph128(pw * 16 + lm,      ks * 32 + g * 8)];
        const short8 a1 = *(const short8*)&xT[ph128(32 + pw * 16 + lm, ks * 32 + g * 8)];
#pragma unroll
        for (int j = 0; j < 3; ++j) {
            const short8 b = *(const short8*)&WT[ph128((ng * 3 + j) * 16 + lm, ks * 32 + g * 8)];
            acc[0][j] = __builtin_amdgcn_mfma_f32_16x16x32_bf16(a0, b, acc[0][j], 0, 0, 0);
            acc[1][j] = __builtin_amdgcn_mfma_f32_16x16x32_bf16(a1, b, acc[1][j], 0, 0, 0);
        }
    }

    // ---- register epilogue: C row = g*4+r, col = lm ----
    const int pbase = p0 + z * 32 + pw * 16 + g * 4;
    const int jp = tile * 32 + z * 16 + pw * 8 + g * 2;

    if (ng == 0) {
        const float bqv = bq[lm];
#pragma unroll
        for (int mi = 0; mi < 2; ++mi)
#pragma unroll
            for (int r = 0; r < 4; ++r)
                Qp[((size_t)n * HWN + pbase + mi * 64 + r) * AD + lm] = f2bf(acc[mi][0][r] + bqv);
        const float bkv = bk[lm];
#pragma unroll
        for (int a = 0; a < 2; ++a) {
            const float m = fmaxf(fmaxf(acc[0][1][2 * a], acc[0][1][2 * a + 1]),
                                  fmaxf(acc[1][1][2 * a], acc[1][1][2 * a + 1])) + bkv;
            Kp[((size_t)n * PJ + jp + a) * AD + lm] = f2bf(m);
        }
        {
            const float bvv = bv[lm];
            const float m0 = fmaxf(fmaxf(acc[0][2][0], acc[0][2][1]),
                                   fmaxf(acc[1][2][0], acc[1][2][1])) + bvv;
            const float m1 = fmaxf(fmaxf(acc[0][2][2], acc[0][2][3]),
                                   fmaxf(acc[1][2][2], acc[1][2][3])) + bvv;
            *(unsigned*)&Vt[((size_t)n * VD + lm) * PJ + jp] = pk2(m0, m1);
        }
    } else {
#pragma unroll
        for (int j = 0; j < 3; ++j) {
            const int dv = (j + 1) * 16 + lm;
            const float bvv = bv[dv];
            const float m0 = fmaxf(fmaxf(acc[0][j][0], acc[0][j][1]),
                                   fmaxf(acc[1][j][0], acc[1][j][1])) + bvv;
            const float m1 = fmaxf(fmaxf(acc[0][j][2], acc[0][j][3]),
                                   fmaxf(acc[1][j][2], acc[1][j][3])) + bvv;
            *(unsigned*)&Vt[((size_t)n * VD + dv) * PJ + jp] = pk2(m0, m1);
        }
    }
}

// ---------------------------------------------------------------------------
// Kernel 2: flash attention + out-proj + residual, all MFMA.
// Grid (64,8), block 256 (4 waves x 16 q).
// ROUND-8 CHANGE: scores computed TRANSPOSED by swapping MFMA operands
// (A-frag and B-frag share per-lane indexing, so staging is unchanged).
// Each lane then owns all 32 scores of one query q=lm:
//   - softmax: local register tree + 2 shfl_xor (was 32 chained shfl)
//   - P round-trip: 8 ds_write_b64 (was 32 conflicted ds_write_b16)
//   - alpha / 1/l moved to O's C-layout rows via 4 __shfl per chunk
// Chunks staged in PAIRS (two 20 KB slots) -> 8 barriers instead of 16.
// ---------------------------------------------------------------------------
__global__ __launch_bounds__(256, 4) void k_attn(
    const float* __restrict__ x,
    const u16* __restrict__ Qp, const u16* __restrict__ Kp, const u16* __restrict__ Vt,
    const float* __restrict__ Wo, const float* __restrict__ bo,
    const float* __restrict__ gma,
    float* __restrict__ out)
{
    __shared__ __align__(16) u16 KV[2][10240];   // per slot: K 2048 | V 8192
    __shared__ __align__(16) u16 PB[4 * 2048];   // per-wave P; reused as O^T

    const int n = blockIdx.y, t = threadIdx.x;
    const int q0b = blockIdx.x * 64;
    const int l = t & 63, w = t >> 6, g = l >> 4, lm = l & 15;

    // Q fragment (g>=2 lanes are the K=16..31 zero pad); used as B-operand now.
    short8 qf = {0, 0, 0, 0, 0, 0, 0, 0};
    if (g < 2)
        qf = *(const short8*)(Qp + ((size_t)n * HWN + q0b + w * 16 + lm) * AD + g * 8);

    // per-lane global source addresses for staging (swizzle on global side)
    const u16* Kg = Kp + (size_t)n * PJ * AD
                  + (size_t)(t >> 1) * AD + ((t & 1) ^ ((t >> 1) & 1)) * 8;
    const u16* Vg0 = Vt + (size_t)n * VD * PJ;

    u16* Pl = PB + w * 2048;

    f32x4 O[4];
#pragma unroll
    for (int i = 0; i < 4; ++i) O[i] = (f32x4){0.f, 0.f, 0.f, 0.f};
    float mr = -1e30f, lr = 0.f;    // per q = lm (replicated across g-lanes)

    for (int pair = 0; pair < 4; ++pair) {
        // ---- stage two chunks ----
#pragma unroll
        for (int s = 0; s < 2; ++s) {
            const int j0 = (pair * 2 + s) * 128;
            stage16(Kg + (size_t)j0 * AD, &KV[s][t * 8]);
#pragma unroll
            for (int i = 0; i < 4; ++i) {
                const int dv = w * 16 + i * 4 + g;
                stage16(Vg0 + (size_t)dv * PJ + j0 + (((l & 15) ^ (dv & 7)) * 8),
                        &KV[s][2048 + (w * 4 + i) * 512 + l * 8]);
            }
        }
        __syncthreads();

#pragma unroll
        for (int s = 0; s < 2; ++s) {
            const u16* Kl = KV[s];
            const u16* Vl = KV[s] + 2048;

            // ---- scores^T: St[row=j-in-tile=4g+r][col=q=lm] ----
            f32x4 St[8];
#pragma unroll
            for (int jt = 0; jt < 8; ++jt) {
                short8 kb = {0, 0, 0, 0, 0, 0, 0, 0};
                if (g < 2) {
                    const int j = jt * 16 + lm;
                    kb = *(const short8*)&Kl[(j * 2 + (g ^ (j & 1))) * 8];
                }
                const f32x4 z4 = (f32x4){0.f, 0.f, 0.f, 0.f};
                St[jt] = __builtin_amdgcn_mfma_f32_16x16x32_bf16(kb, qf, z4, 0, 0, 0);
            }

            // ---- online softmax, per-lane over 32 regs + 2 shfl ----
            float cm = St[0][0];
#pragma unroll
            for (int jt = 0; jt < 8; ++jt)
#pragma unroll
                for (int r = 0; r < 4; ++r) cm = fmaxf(cm, St[jt][r]);
            cm = fmaxf(cm, __shfl_xor(cm, 16));
            cm = fmaxf(cm, __shfl_xor(cm, 32));
            const float nm = fmaxf(mr, cm);
            const float al = __expf(mr - nm);
            mr = nm;
            float sum = 0.f;
#pragma unroll
            for (int jt = 0; jt < 8; ++jt)
#pragma unroll
                for (int r = 0; r < 4; ++r) {
                    const float p = __expf(St[jt][r] - nm);
                    St[jt][r] = p;
                    sum += p;
                }
            sum += __shfl_xor(sum, 16);
            sum += __shfl_xor(sum, 32);
            lr = lr * al + sum;

            // ---- rescale O (rows q = 4g+r) with alpha fetched from lane q ----
#pragma unroll
            for (int r = 0; r < 4; ++r) {
                const float ar = __shfl(al, g * 4 + r);
                O[0][r] *= ar; O[1][r] *= ar; O[2][r] *= ar; O[3][r] *= ar;
            }

            // ---- P pack + b64 write: row q=lm, cols jt*16+4g..+3 ----
#pragma unroll
            for (int jt = 0; jt < 8; ++jt) {
                uint2 dw;
                dw.x = pk2(St[jt][0], St[jt][1]);
                dw.y = pk2(St[jt][2], St[jt][3]);
                *(uint2*)&Pl[lm * 128 + (((2 * jt + (g >> 1)) ^ (lm & 7)) << 3) + 4 * (g & 1)] = dw;
            }

            // ---- P @ V (A-frag reads unchanged: conflict-free b128) ----
#pragma unroll
            for (int ks = 0; ks < 4; ++ks) {
                const short8 pf = *(const short8*)&Pl[ph128(lm, ks * 32 + g * 8)];
#pragma unroll
                for (int dt = 0; dt < 4; ++dt) {
                    const short8 vf = *(const short8*)&Vl[ph128(dt * 16 + lm, ks * 32 + g * 8)];
                    O[dt] = __builtin_amdgcn_mfma_f32_16x16x32_bf16(pf, vf, O[dt], 0, 0, 0);
                }
            }
        }
        __syncthreads();   // all waves done with both slots before next stage
    }

    // ---- normalize (1/l fetched from lane q), O^T -> per-wave LDS ----
    const float invq = 1.f / lr;
    u16* Ol = Pl;
#pragma unroll
    for (int r = 0; r < 4; ++r) {
        const float inv = __shfl(invq, g * 4 + r);
        const int row = g * 4 + r;
#pragma unroll
        for (int dt = 0; dt < 4; ++dt)
            Ol[ph64(row, dt * 16 + lm)] = f2bf(O[dt][r] * inv);
    }
    // ---- stage WoT[c][dv] into KV (dead after final barrier) ----
    u16* WoTl = (u16*)KV;
#pragma unroll
    for (int it = 0; it < 8; ++it) {
        const int idx = t + 256 * it;
        const int c4 = idx & 31, dv = idx >> 5;
        const float4 v = *(const float4*)(Wo + dv * CC + c4 * 4);
        WoTl[ph64(c4 * 4 + 0, dv)] = f2bf(v.x);
        WoTl[ph64(c4 * 4 + 1, dv)] = f2bf(v.y);
        WoTl[ph64(c4 * 4 + 2, dv)] = f2bf(v.z);
        WoTl[ph64(c4 * 4 + 3, dv)] = f2bf(v.w);
    }
    __syncthreads();

    // ---- out-proj: D[c][q] = WoT(c,dv) @ O^T(dv,q); residual + store ----
    const float gm = gma[0];
#pragma unroll
    for (int mt = 0; mt < 8; ++mt) {
        float xr[4];
        const size_t obase = ((size_t)n * CC + mt * 16 + g * 4) * HWN + q0b + w * 16 + lm;
#pragma unroll
        for (int r = 0; r < 4; ++r) xr[r] = x[obase + (size_t)r * HWN];
        f32x4 D = (f32x4){0.f, 0.f, 0.f, 0.f};
#pragma unroll
        for (int ks = 0; ks < 2; ++ks) {
            const short8 af = *(const short8*)&WoTl[ph64(mt * 16 + lm, ks * 32 + g * 8)];
            const short8 bf = *(const short8*)&Ol[ph64(lm, ks * 32 + g * 8)];
            D = __builtin_amdgcn_mfma_f32_16x16x32_bf16(af, bf, D, 0, 0, 0);
        }
#pragma unroll
        for (int r = 0; r < 4; ++r) {
            const int c = mt * 16 + g * 4 + r;
            out[obase + (size_t)r * HWN] = xr[r] + gm * (D[r] + bo[c]);
        }
    }
}

extern "C" void kernel_launch(void* const* d_in, const int* in_sizes, int n_in,
                              void* d_out, int out_size, void* d_ws, size_t ws_size,
                              hipStream_t stream) {
    const float* x     = (const float*)d_in[0];
    const float* Wq    = (const float*)d_in[1];
    const float* bq    = (const float*)d_in[2];
    const float* Wk    = (const float*)d_in[3];
    const float* bk    = (const float*)d_in[4];
    const float* Wv    = (const float*)d_in[5];
    const float* bv    = (const float*)d_in[6];
    const float* Wo    = (const float*)d_in[7];
    const float* bo    = (const float*)d_in[8];
    const float* gamma = (const float*)d_in[9];
    float* out = (float*)d_out;

    u16* Qp = (u16*)d_ws;                        // 8*4096*16 bf16 = 1 MB
    u16* Kp = Qp + (size_t)NB * HWN * AD;        // 8*1024*16 bf16 = 256 KB
    u16* Vt = Kp + (size_t)NB * PJ * AD;         // 8*64*1024 bf16 = 1 MB

    k_proj<<<dim3(32, NB, 2), 256, 0, stream>>>(x, Wq, bq, Wk, bk, Wv, bv, Qp, Kp, Vt);
    k_attn<<<dim3(64, NB), 256, 0, stream>>>(x, Qp, Kp, Vt, Wo, bo, gamma, out);
}